// Round 7
// baseline (107.785 us; speedup 1.0000x reference)
//
#include <hip/hip_runtime.h>
#include <hip/hip_bf16.h>

#define V   32768       // 32*32*32 coarse voxels
#define FV  262144      // 64^3 fine voxels
#define PD  34          // padded dim
#define PP  1156        // 34*34
#define NP  39304       // 34^3

#define NBA 154         // y1p role blocks (ceil(NP/256))
#define NBX 128         // xp role blocks  (V/256)
#define NBW 216         // A-frag permute role blocks (55296/256)

typedef __attribute__((ext_vector_type(8))) short bf16x8;
typedef __attribute__((ext_vector_type(4))) float f32x4;

__device__ __forceinline__ unsigned short f2bf(float f) {
    __hip_bfloat16 h = __float2bfloat16(f);   // RNE
    return __builtin_bit_cast(unsigned short, h);
}

// ---------------------------------------------------------------------------
// Kernel P (fused prep), role by blockIdx.x:
//  [0,NBA):        y1p[p][c] = bf16(bc[c] + Wc.x[v(p)])  over PADDED voxels,
//                  halo rows written as zeros.
//  [NBA,NBA+NBX):  xp[v][oc] = Wp.x[v]                    (f32, voxel-major)
//  [NBA+NBX,...):  Ab2[half][wmh][tap][f][lane][e] = bf16(We frag gather)
//                  (MFMA A-fragment-major: f = ks*4+i, e = 0..7 contiguous)
// ---------------------------------------------------------------------------
__global__ __launch_bounds__(256) void kP(const float* __restrict__ x,
                                          const float* __restrict__ Wc,
                                          const float* __restrict__ bc,
                                          const float* __restrict__ Wp,
                                          const float* __restrict__ We,
                                          unsigned short* __restrict__ y1p,
                                          float* __restrict__ xp,
                                          unsigned short* __restrict__ Ab2) {
    __shared__ __align__(16) float sw[64 * 64];
    __shared__ float sbc[64];
    int tid = threadIdx.x;
    int bid = blockIdx.x;

    if (bid < NBA) {
        // ---- y1p role ----
        for (int i = tid; i < 64 * 64; i += 256) sw[i] = Wc[i];
        for (int i = tid; i < 64; i += 256) sbc[i] = bc[i];
        __syncthreads();

        int p = bid * 256 + tid;
        if (p >= NP) return;
        int pz = p / PP, rr = p - pz * PP;
        int py = rr / PD, px = rr - py * PD;
        unsigned short* dst = y1p + (size_t)p * 64;

        if (pz == 0 || pz == 33 || py == 0 || py == 33 || px == 0 || px == 33) {
            uint4 z4 = make_uint4(0, 0, 0, 0);
#pragma unroll
            for (int q = 0; q < 8; ++q) *(uint4*)(dst + q * 8) = z4;
            return;
        }
        int v = (pz - 1) * 1024 + (py - 1) * 32 + (px - 1);
        float xv[64];
#pragma unroll
        for (int c = 0; c < 64; ++c) xv[c] = x[c * V + v];

        unsigned int row[32];
        for (int m = 0; m < 64; m += 2) {
            float a0 = sbc[m], a1 = sbc[m + 1];
#pragma unroll
            for (int c4 = 0; c4 < 16; ++c4) {
                float4 w0 = *(const float4*)(sw + m * 64 + c4 * 4);
                float4 w1 = *(const float4*)(sw + (m + 1) * 64 + c4 * 4);
                a0 += w0.x * xv[c4 * 4] + w0.y * xv[c4 * 4 + 1] +
                      w0.z * xv[c4 * 4 + 2] + w0.w * xv[c4 * 4 + 3];
                a1 += w1.x * xv[c4 * 4] + w1.y * xv[c4 * 4 + 1] +
                      w1.z * xv[c4 * 4 + 2] + w1.w * xv[c4 * 4 + 3];
            }
            row[m >> 1] = (unsigned int)f2bf(a0) | ((unsigned int)f2bf(a1) << 16);
        }
#pragma unroll
        for (int q = 0; q < 8; ++q)
            *(uint4*)(dst + q * 8) =
                make_uint4(row[q * 4], row[q * 4 + 1], row[q * 4 + 2], row[q * 4 + 3]);

    } else if (bid < NBA + NBX) {
        // ---- xp role ----
        for (int i = tid; i < 32 * 64; i += 256) sw[i] = Wp[i];
        __syncthreads();

        int v = (bid - NBA) * 256 + tid;
        float xv[64];
#pragma unroll
        for (int c = 0; c < 64; ++c) xv[c] = x[c * V + v];

        float pacc[32];
        for (int oc = 0; oc < 32; ++oc) {
            float acc = 0.f;
#pragma unroll
            for (int c4 = 0; c4 < 16; ++c4) {
                float4 w0 = *(const float4*)(sw + oc * 64 + c4 * 4);
                acc += w0.x * xv[c4 * 4] + w0.y * xv[c4 * 4 + 1] +
                       w0.z * xv[c4 * 4 + 2] + w0.w * xv[c4 * 4 + 3];
            }
            pacc[oc] = acc;
        }
#pragma unroll
        for (int q = 0; q < 8; ++q)
            *(float4*)(xp + (size_t)v * 32 + q * 4) =
                make_float4(pacc[q * 4], pacc[q * 4 + 1], pacc[q * 4 + 2], pacc[q * 4 + 3]);

    } else {
        // ---- A-frag permute role ----
        // u -> (half, wmh, tap, f, lane); thread writes one 16B frag (8 bf16).
        int u = (bid - NBA - NBX) * 256 + tid;       // 0..55295
        int lane = u & 63;
        int f = (u >> 6) & 7;
        int tmp = u >> 9;                            // 0..107
        int tap = tmp % 27;
        int rest = tmp / 27;                         // 0..3
        int wmh = rest & 1, half = rest >> 1;
        int ks = f >> 2, i = f & 3;
        int m = half * 88 + wmh * 64 + i * 16 + (lane & 15);
        int c0 = (ks * 4 + (lane >> 4)) * 8;
        unsigned int pk[4];
#pragma unroll
        for (int p2 = 0; p2 < 4; ++p2) {
            unsigned int lo = f2bf(We[(m * 64 + c0 + 2 * p2) * 27 + tap]);
            unsigned int hi = f2bf(We[(m * 64 + c0 + 2 * p2 + 1) * 27 + tap]);
            pk[p2] = lo | (hi << 16);
        }
        ((uint4*)Ab2)[u] = make_uint4(pk[0], pk[1], pk[2], pk[3]);
    }
}

// ---------------------------------------------------------------------------
// Kernel G: implicit-GEMM 3x3x3 conv; A in registers, B in a static LDS halo.
// N-tile = 4x4x8 voxel patch (128). Halo box 6x6x10 = 360 padded voxels
// staged ONCE (chunk-XOR swizzle q^=(p&7)); all 27 taps read shifted
// ds_read_b128 from it.  A fragments stream global->VGPR (coalesced
// dwordx4 from frag-major Ab2, L2-resident), register double-buffered.
// NO barriers inside the 27-tap loop.
// 4 waves (2x2), wave tile 64x64, 16x16x32 bf16 MFMA.
// blockIdx.y: m0 = 0 or 88 (rows 88..127 computed twice, identical values).
// ---------------------------------------------------------------------------
__global__ __launch_bounds__(256) void kG(const unsigned short* __restrict__ Ab2,
                                          const unsigned short* __restrict__ y1p,
                                          const float* __restrict__ be,
                                          float* __restrict__ y2) {
    __shared__ unsigned short sH[360 * 64];      // 45 KB halo, swizzled chunks
    int tid = threadIdx.x, lane = tid & 63, wid = tid >> 6;
    int half = blockIdx.y;
    int m0 = half ? 88 : 0;
    int bidx = blockIdx.x;
    int bw = bidx & 3, by = (bidx >> 2) & 7, bz = bidx >> 5;

    // ---- B halo staging: 360 voxels x 8 chunks = 2880 uint4 units ----
    for (int it = 0; it < 12; ++it) {
        int u = it * 256 + tid;
        if (u < 2880) {
            int q = u & 7, p = u >> 3;
            int hw = p % 10, t2 = p / 10;
            int hh = t2 % 6, hz = t2 / 6;
            size_t src = ((size_t)(bz * 4 + hz) * PP + (by * 4 + hh) * PD + (bw * 8 + hw)) * 64
                         + q * 8;
            uint4 val = *(const uint4*)(y1p + src);
            *(uint4*)((char*)sH + (p * 8 + (q ^ (p & 7))) * 16) = val;
        }
    }

    int wmh = wid >> 1;            // 0/1 -> wm = wmh*64
    int wn  = (wid & 1) * 64;

    // A fragment stream base: frag (tap,f) at Aptr[(tap*8+f)*64]
    const uint4* Aptr = (const uint4*)Ab2 + (size_t)(half * 2 + wmh) * 27 * 8 * 64 + lane;

    int p0[4], vv[4];
#pragma unroll
    for (int j = 0; j < 4; ++j) {
        int n = wn + j * 16 + (lane & 15);
        int zi = n >> 5, hi = (n >> 3) & 3, wi = n & 7;
        p0[j] = zi * 60 + hi * 10 + wi;
        vv[j] = (bz * 4 + zi) * 1024 + (by * 4 + hi) * 32 + bw * 8 + wi;
    }

    f32x4 acc[4][4] = {};
    uint4 afA[8], afB[8];

#pragma unroll
    for (int f = 0; f < 8; ++f) afA[f] = Aptr[f * 64];   // tap 0

    __syncthreads();    // halo resident; the ONLY block-wide barrier

#define COMPUTE(KT, AF)                                                       \
    {                                                                         \
        int dz = (KT) / 9, rem = (KT) - dz * 9;                               \
        int dy = rem / 3, dx = rem - dy * 3;                                  \
        int pofs = dz * 60 + dy * 10 + dx;                                    \
        _Pragma("unroll")                                                     \
        for (int ks = 0; ks < 2; ++ks) {                                      \
            bf16x8 b[4];                                                      \
            int cc = ks * 4 + (lane >> 4);                                    \
            _Pragma("unroll")                                                 \
            for (int j = 0; j < 4; ++j) {                                     \
                int p = p0[j] + pofs;                                         \
                b[j] = *(const bf16x8*)(sH + p * 64 + (cc ^ (p & 7)) * 8);    \
            }                                                                 \
            _Pragma("unroll")                                                 \
            for (int i = 0; i < 4; ++i) {                                     \
                bf16x8 a = __builtin_bit_cast(bf16x8, AF[ks * 4 + i]);        \
                _Pragma("unroll")                                             \
                for (int j = 0; j < 4; ++j)                                   \
                    acc[i][j] = __builtin_amdgcn_mfma_f32_16x16x32_bf16(      \
                        a, b[j], acc[i][j], 0, 0, 0);                         \
            }                                                                 \
        }                                                                     \
    }

    for (int kt = 0; kt < 27; kt += 2) {
        int t1 = (kt + 1 < 27) ? kt + 1 : 26;
#pragma unroll
        for (int f = 0; f < 8; ++f) afB[f] = Aptr[(t1 * 8 + f) * 64];
        COMPUTE(kt, afA);
        int t2 = (kt + 2 < 27) ? kt + 2 : 26;
#pragma unroll
        for (int f = 0; f < 8; ++f) afA[f] = Aptr[(t2 * 8 + f) * 64];
        if (kt + 1 < 27) COMPUTE(kt + 1, afB);
    }
#undef COMPUTE

    // C/D layout: col = lane&15 (n side), row = (lane>>4)*4 + reg (m side)
#pragma unroll
    for (int i = 0; i < 4; ++i) {
#pragma unroll
        for (int r = 0; r < 4; ++r) {
            int m = m0 + wmh * 64 + i * 16 + (lane >> 4) * 4 + r;
            float bv = be[m];
#pragma unroll
            for (int j = 0; j < 4; ++j)
                y2[(size_t)m * V + vv[j]] = acc[i][j][r] + bv;
        }
    }
}

// ---------------------------------------------------------------------------
// Kernel C: pixel-shuffle + softmax(27) + CARAFE combine, LDS-staged.
// Block = one (d,h) cell-row (1024 blocks, 256 threads).
// ---------------------------------------------------------------------------
__global__ __launch_bounds__(256) void kC(const float* __restrict__ y2,
                                          const float* __restrict__ xp,
                                          float* __restrict__ out) {
    __shared__ float  slog[8][27][32];   // 27.6 KB
    __shared__ float4 sxp[9][32][8];     // 36.9 KB
    int t = threadIdx.x;
    int bid = blockIdx.x;
    int d = bid >> 5, h = bid & 31;
    int g = t >> 5, w = t & 31;

    // phase 1a: logits (coalesced 128B segments)
    int vc = d * 1024 + h * 32 + w;
#pragma unroll
    for (int it = 0; it < 27; ++it)
        slog[g][it][w] = y2[(size_t)(it * 8 + g) * V + vc];

    // phase 1b: xp neighborhood rows (fully coalesced float4)
    {
        int xx = t >> 3, q = t & 7;
#pragma unroll
        for (int zy = 0; zy < 9; ++zy) {
            int zi = zy / 3, yi = zy - zi * 3;
            int zz = min(max(d + zi - 1, 0), 31);
            int yy = min(max(h + yi - 1, 0), 31);
            float4 v4 = *(const float4*)(xp + (size_t)(zz * 1024 + yy * 32 + xx) * 32 + q * 4);
            sxp[zy][xx][q ^ (xx & 7)] = v4;
        }
    }
    __syncthreads();

    // phase 2: softmax over 27 taps for (sub=g, cell w), in place
    {
        float lg[27];
#pragma unroll
        for (int tp = 0; tp < 27; ++tp) lg[tp] = slog[g][tp][w];
        float m = lg[0];
#pragma unroll
        for (int tp = 1; tp < 27; ++tp) m = fmaxf(m, lg[tp]);
        float s = 0.f;
#pragma unroll
        for (int tp = 0; tp < 27; ++tp) { lg[tp] = __expf(lg[tp] - m); s += lg[tp]; }
        float inv = 1.f / s;
#pragma unroll
        for (int tp = 0; tp < 27; ++tp) slog[g][tp][w] = lg[tp] * inv;
    }
    __syncthreads();

    // phase 3: combine
    float acc[8][4] = {};
#pragma unroll
    for (int zy = 0; zy < 9; ++zy) {
#pragma unroll
        for (int dx = 0; dx < 3; ++dx) {
            int tap = zy * 3 + dx;
            int xx = min(max(w + dx - 1, 0), 31);
            float4 xv = sxp[zy][xx][g ^ (xx & 7)];
            float wn[8];
#pragma unroll
            for (int sub = 0; sub < 8; ++sub) wn[sub] = slog[sub][tap][w];
#pragma unroll
            for (int sub = 0; sub < 8; ++sub) {
                acc[sub][0] += wn[sub] * xv.x;
                acc[sub][1] += wn[sub] * xv.y;
                acc[sub][2] += wn[sub] * xv.z;
                acc[sub][3] += wn[sub] * xv.w;
            }
        }
    }

    // epilogue: pair l=0/1 into float2 (fx = 2w, 2w+1)
    int fzb = 2 * d, fyb = 2 * h;
#pragma unroll
    for (int sp = 0; sp < 4; ++sp) {          // sub pair (2sp, 2sp+1), sp = i*2+j
        int i = sp >> 1, j = sp & 1;
        size_t ob = (size_t)(fzb + i) * 4096 + (size_t)(fyb + j) * 64 + 2 * w;
#pragma unroll
        for (int k = 0; k < 4; ++k) {
            float2 v2 = make_float2(acc[2 * sp][k], acc[2 * sp + 1][k]);
            *(float2*)(out + (size_t)(g * 4 + k) * FV + ob) = v2;
        }
    }
}

extern "C" void kernel_launch(void* const* d_in, const int* in_sizes, int n_in,
                              void* d_out, int out_size, void* d_ws, size_t ws_size,
                              hipStream_t stream) {
    const float* x  = (const float*)d_in[0];
    const float* Wc = (const float*)d_in[1];
    const float* bc = (const float*)d_in[2];
    const float* We = (const float*)d_in[3];
    const float* be = (const float*)d_in[4];
    const float* Wp = (const float*)d_in[5];
    float* out = (float*)d_out;

    float* ws = (float*)d_ws;
    float* y2 = ws;                                        // 216*V f32 = 28.3 MB
    float* xp = y2 + (size_t)216 * V;                      // 32*V  f32 =  4 MB
    unsigned short* Ab2 = (unsigned short*)(xp + (size_t)32 * V);  // 55296*8 bf16 = 0.85 MB
    unsigned short* y1p = Ab2 + (size_t)55296 * 8;         // 34^3*64 bf16 = 5 MB

    kP<<<NBA + NBX + NBW, 256, 0, stream>>>(x, Wc, bc, Wp, We, y1p, xp, Ab2);
    kG<<<dim3(256, 2), 256, 0, stream>>>(Ab2, y1p, be, y2);
    kC<<<1024, 256, 0, stream>>>(y2, xp, out);
}

// Round 8
// 97.733 us; speedup vs baseline: 1.1029x; 1.1029x over previous
//
#include <hip/hip_runtime.h>
#include <hip/hip_bf16.h>

#define V   32768       // 32*32*32 coarse voxels
#define FV  262144      // 64^3 fine voxels
#define PD  34          // padded dim
#define PP  1156        // 34*34
#define NP  39304       // 34^3

#define NBA 154         // y1p role blocks (ceil(NP/256))
#define NBX 128         // xp role blocks  (V/256)
#define NBW 216         // A-frag permute role blocks (55296/256)

typedef __attribute__((ext_vector_type(8))) short bf16x8;
typedef __attribute__((ext_vector_type(4))) float f32x4;

__device__ __forceinline__ unsigned short f2bf(float f) {
    __hip_bfloat16 h = __float2bfloat16(f);   // RNE
    return __builtin_bit_cast(unsigned short, h);
}

// ---------------------------------------------------------------------------
// Kernel P (fused prep), role by blockIdx.x:
//  [0,NBA):        y1p[p][c] = bf16(bc[c] + Wc.x[v(p)])  over PADDED voxels,
//                  halo rows written as zeros.
//  [NBA,NBA+NBX):  xp[v][oc] = Wp.x[v]                    (f32, voxel-major)
//  [NBA+NBX,...):  Ab2[half][wmh][tap][f][lane][e] = bf16(We frag gather)
//                  (MFMA A-fragment-major: f = ks*4+i, e = 0..7 contiguous)
// ---------------------------------------------------------------------------
__global__ __launch_bounds__(256) void kP(const float* __restrict__ x,
                                          const float* __restrict__ Wc,
                                          const float* __restrict__ bc,
                                          const float* __restrict__ Wp,
                                          const float* __restrict__ We,
                                          unsigned short* __restrict__ y1p,
                                          float* __restrict__ xp,
                                          unsigned short* __restrict__ Ab2) {
    __shared__ __align__(16) float sw[64 * 64];
    __shared__ float sbc[64];
    int tid = threadIdx.x;
    int bid = blockIdx.x;

    if (bid < NBA) {
        // ---- y1p role ----
        for (int i = tid; i < 64 * 64; i += 256) sw[i] = Wc[i];
        for (int i = tid; i < 64; i += 256) sbc[i] = bc[i];
        __syncthreads();

        int p = bid * 256 + tid;
        if (p >= NP) return;
        int pz = p / PP, rr = p - pz * PP;
        int py = rr / PD, px = rr - py * PD;
        unsigned short* dst = y1p + (size_t)p * 64;

        if (pz == 0 || pz == 33 || py == 0 || py == 33 || px == 0 || px == 33) {
            uint4 z4 = make_uint4(0, 0, 0, 0);
#pragma unroll
            for (int q = 0; q < 8; ++q) *(uint4*)(dst + q * 8) = z4;
            return;
        }
        int v = (pz - 1) * 1024 + (py - 1) * 32 + (px - 1);
        float xv[64];
#pragma unroll
        for (int c = 0; c < 64; ++c) xv[c] = x[c * V + v];

        unsigned int row[32];
        for (int m = 0; m < 64; m += 2) {
            float a0 = sbc[m], a1 = sbc[m + 1];
#pragma unroll
            for (int c4 = 0; c4 < 16; ++c4) {
                float4 w0 = *(const float4*)(sw + m * 64 + c4 * 4);
                float4 w1 = *(const float4*)(sw + (m + 1) * 64 + c4 * 4);
                a0 += w0.x * xv[c4 * 4] + w0.y * xv[c4 * 4 + 1] +
                      w0.z * xv[c4 * 4 + 2] + w0.w * xv[c4 * 4 + 3];
                a1 += w1.x * xv[c4 * 4] + w1.y * xv[c4 * 4 + 1] +
                      w1.z * xv[c4 * 4 + 2] + w1.w * xv[c4 * 4 + 3];
            }
            row[m >> 1] = (unsigned int)f2bf(a0) | ((unsigned int)f2bf(a1) << 16);
        }
#pragma unroll
        for (int q = 0; q < 8; ++q)
            *(uint4*)(dst + q * 8) =
                make_uint4(row[q * 4], row[q * 4 + 1], row[q * 4 + 2], row[q * 4 + 3]);

    } else if (bid < NBA + NBX) {
        // ---- xp role ----
        for (int i = tid; i < 32 * 64; i += 256) sw[i] = Wp[i];
        __syncthreads();

        int v = (bid - NBA) * 256 + tid;
        float xv[64];
#pragma unroll
        for (int c = 0; c < 64; ++c) xv[c] = x[c * V + v];

        float pacc[32];
        for (int oc = 0; oc < 32; ++oc) {
            float acc = 0.f;
#pragma unroll
            for (int c4 = 0; c4 < 16; ++c4) {
                float4 w0 = *(const float4*)(sw + oc * 64 + c4 * 4);
                acc += w0.x * xv[c4 * 4] + w0.y * xv[c4 * 4 + 1] +
                       w0.z * xv[c4 * 4 + 2] + w0.w * xv[c4 * 4 + 3];
            }
            pacc[oc] = acc;
        }
#pragma unroll
        for (int q = 0; q < 8; ++q)
            *(float4*)(xp + (size_t)v * 32 + q * 4) =
                make_float4(pacc[q * 4], pacc[q * 4 + 1], pacc[q * 4 + 2], pacc[q * 4 + 3]);

    } else {
        // ---- A-frag permute role ----
        // u -> (half, wmh, tap, f, lane); thread writes one 16B frag (8 bf16).
        int u = (bid - NBA - NBX) * 256 + tid;       // 0..55295
        int lane = u & 63;
        int f = (u >> 6) & 7;
        int tmp = u >> 9;                            // 0..107
        int tap = tmp % 27;
        int rest = tmp / 27;                         // 0..3
        int wmh = rest & 1, half = rest >> 1;
        int ks = f >> 2, i = f & 3;
        int m = half * 88 + wmh * 64 + i * 16 + (lane & 15);
        int c0 = (ks * 4 + (lane >> 4)) * 8;
        unsigned int pk[4];
#pragma unroll
        for (int p2 = 0; p2 < 4; ++p2) {
            unsigned int lo = f2bf(We[(m * 64 + c0 + 2 * p2) * 27 + tap]);
            unsigned int hi = f2bf(We[(m * 64 + c0 + 2 * p2 + 1) * 27 + tap]);
            pk[p2] = lo | (hi << 16);
        }
        ((uint4*)Ab2)[u] = make_uint4(pk[0], pk[1], pk[2], pk[3]);
    }
}

// ---------------------------------------------------------------------------
// Kernel G: implicit-GEMM 3x3x3 conv; A in registers, B in a static LDS halo.
// 512 threads = 8 waves, wave grid 2(M-half) x 4(N-quarter), wave tile 64x32.
// N-tile = 4x4x8 voxel patch (128). Halo box 6x6x10 = 360 padded voxels
// staged ONCE (chunk-XOR swizzle q^=(p&7)); all 27 taps read shifted
// ds_read_b128 from it.  A fragments stream global->VGPR (coalesced
// dwordx4 from frag-major Ab2, L2-resident), register double-buffered.
// NO barriers inside the 27-tap loop.  4 waves/SIMD for latency hiding.
// blockIdx.y: m0 = 0 or 88 (rows 88..127 computed twice, identical values).
// ---------------------------------------------------------------------------
__global__ __launch_bounds__(512, 4) void kG(const unsigned short* __restrict__ Ab2,
                                             const unsigned short* __restrict__ y1p,
                                             const float* __restrict__ be,
                                             float* __restrict__ y2) {
    __shared__ unsigned short sH[360 * 64];      // 45 KB halo, swizzled chunks
    int tid = threadIdx.x, lane = tid & 63, wid = tid >> 6;   // wid 0..7
    int half = blockIdx.y;
    int m0 = half ? 88 : 0;
    int bidx = blockIdx.x;
    int bw = bidx & 3, by = (bidx >> 2) & 7, bz = bidx >> 5;

    // ---- B halo staging: 360 voxels x 8 chunks = 2880 uint4 units ----
    for (int it = 0; it < 6; ++it) {
        int u = it * 512 + tid;
        if (u < 2880) {
            int q = u & 7, p = u >> 3;
            int hw = p % 10, t2 = p / 10;
            int hh = t2 % 6, hz = t2 / 6;
            size_t src = ((size_t)(bz * 4 + hz) * PP + (by * 4 + hh) * PD + (bw * 8 + hw)) * 64
                         + q * 8;
            uint4 val = *(const uint4*)(y1p + src);
            *(uint4*)((char*)sH + (p * 8 + (q ^ (p & 7))) * 16) = val;
        }
    }

    int wmh = wid >> 2;            // 0/1 -> m-half of the 128-row tile
    int wn  = (wid & 3) * 32;      // n-quarter

    // A fragment stream base: frag (tap,f) at Aptr[(tap*8+f)*64]
    const uint4* Aptr = (const uint4*)Ab2 + (size_t)(half * 2 + wmh) * 27 * 8 * 64 + lane;

    int p0[2], vv[2];
#pragma unroll
    for (int j = 0; j < 2; ++j) {
        int n = wn + j * 16 + (lane & 15);
        int zi = n >> 5, hi = (n >> 3) & 3, wi = n & 7;
        p0[j] = zi * 60 + hi * 10 + wi;
        vv[j] = (bz * 4 + zi) * 1024 + (by * 4 + hi) * 32 + bw * 8 + wi;
    }

    f32x4 acc[4][2] = {};
    uint4 afA[8], afB[8];

#pragma unroll
    for (int f = 0; f < 8; ++f) afA[f] = Aptr[f * 64];   // tap 0

    __syncthreads();    // halo resident; the ONLY block-wide barrier

#define COMPUTE(KT, AF)                                                       \
    {                                                                         \
        int dz = (KT) / 9, rem = (KT) - dz * 9;                               \
        int dy = rem / 3, dx = rem - dy * 3;                                  \
        int pofs = dz * 60 + dy * 10 + dx;                                    \
        _Pragma("unroll")                                                     \
        for (int ks = 0; ks < 2; ++ks) {                                      \
            bf16x8 b[2];                                                      \
            int cc = ks * 4 + (lane >> 4);                                    \
            _Pragma("unroll")                                                 \
            for (int j = 0; j < 2; ++j) {                                     \
                int p = p0[j] + pofs;                                         \
                b[j] = *(const bf16x8*)(sH + p * 64 + (cc ^ (p & 7)) * 8);    \
            }                                                                 \
            _Pragma("unroll")                                                 \
            for (int i = 0; i < 4; ++i) {                                     \
                bf16x8 a = __builtin_bit_cast(bf16x8, AF[ks * 4 + i]);        \
                _Pragma("unroll")                                             \
                for (int j = 0; j < 2; ++j)                                   \
                    acc[i][j] = __builtin_amdgcn_mfma_f32_16x16x32_bf16(      \
                        a, b[j], acc[i][j], 0, 0, 0);                         \
            }                                                                 \
        }                                                                     \
    }

    for (int kt = 0; kt < 27; kt += 2) {
        int t1 = (kt + 1 < 27) ? kt + 1 : 26;
#pragma unroll
        for (int f = 0; f < 8; ++f) afB[f] = Aptr[(t1 * 8 + f) * 64];
        COMPUTE(kt, afA);
        int t2 = (kt + 2 < 27) ? kt + 2 : 26;
#pragma unroll
        for (int f = 0; f < 8; ++f) afA[f] = Aptr[(t2 * 8 + f) * 64];
        if (kt + 1 < 27) COMPUTE(kt + 1, afB);
    }
#undef COMPUTE

    // C/D layout: col = lane&15 (n side), row = (lane>>4)*4 + reg (m side)
#pragma unroll
    for (int i = 0; i < 4; ++i) {
#pragma unroll
        for (int r = 0; r < 4; ++r) {
            int m = m0 + wmh * 64 + i * 16 + (lane >> 4) * 4 + r;
            float bv = be[m];
#pragma unroll
            for (int j = 0; j < 2; ++j)
                y2[(size_t)m * V + vv[j]] = acc[i][j][r] + bv;
        }
    }
}

// ---------------------------------------------------------------------------
// Kernel C: pixel-shuffle + softmax(27) + CARAFE combine, LDS-staged.
// Block = one (d,h) cell-row (1024 blocks, 256 threads).
// ---------------------------------------------------------------------------
__global__ __launch_bounds__(256) void kC(const float* __restrict__ y2,
                                          const float* __restrict__ xp,
                                          float* __restrict__ out) {
    __shared__ float  slog[8][27][32];   // 27.6 KB
    __shared__ float4 sxp[9][32][8];     // 36.9 KB
    int t = threadIdx.x;
    int bid = blockIdx.x;
    int d = bid >> 5, h = bid & 31;
    int g = t >> 5, w = t & 31;

    // phase 1a: logits (coalesced 128B segments)
    int vc = d * 1024 + h * 32 + w;
#pragma unroll
    for (int it = 0; it < 27; ++it)
        slog[g][it][w] = y2[(size_t)(it * 8 + g) * V + vc];

    // phase 1b: xp neighborhood rows (fully coalesced float4)
    {
        int xx = t >> 3, q = t & 7;
#pragma unroll
        for (int zy = 0; zy < 9; ++zy) {
            int zi = zy / 3, yi = zy - zi * 3;
            int zz = min(max(d + zi - 1, 0), 31);
            int yy = min(max(h + yi - 1, 0), 31);
            float4 v4 = *(const float4*)(xp + (size_t)(zz * 1024 + yy * 32 + xx) * 32 + q * 4);
            sxp[zy][xx][q ^ (xx & 7)] = v4;
        }
    }
    __syncthreads();

    // phase 2: softmax over 27 taps for (sub=g, cell w), in place
    {
        float lg[27];
#pragma unroll
        for (int tp = 0; tp < 27; ++tp) lg[tp] = slog[g][tp][w];
        float m = lg[0];
#pragma unroll
        for (int tp = 1; tp < 27; ++tp) m = fmaxf(m, lg[tp]);
        float s = 0.f;
#pragma unroll
        for (int tp = 0; tp < 27; ++tp) { lg[tp] = __expf(lg[tp] - m); s += lg[tp]; }
        float inv = 1.f / s;
#pragma unroll
        for (int tp = 0; tp < 27; ++tp) slog[g][tp][w] = lg[tp] * inv;
    }
    __syncthreads();

    // phase 3: combine
    float acc[8][4] = {};
#pragma unroll
    for (int zy = 0; zy < 9; ++zy) {
#pragma unroll
        for (int dx = 0; dx < 3; ++dx) {
            int tap = zy * 3 + dx;
            int xx = min(max(w + dx - 1, 0), 31);
            float4 xv = sxp[zy][xx][g ^ (xx & 7)];
            float wn[8];
#pragma unroll
            for (int sub = 0; sub < 8; ++sub) wn[sub] = slog[sub][tap][w];
#pragma unroll
            for (int sub = 0; sub < 8; ++sub) {
                acc[sub][0] += wn[sub] * xv.x;
                acc[sub][1] += wn[sub] * xv.y;
                acc[sub][2] += wn[sub] * xv.z;
                acc[sub][3] += wn[sub] * xv.w;
            }
        }
    }

    // epilogue: pair l=0/1 into float2 (fx = 2w, 2w+1)
    int fzb = 2 * d, fyb = 2 * h;
#pragma unroll
    for (int sp = 0; sp < 4; ++sp) {          // sub pair (2sp, 2sp+1), sp = i*2+j
        int i = sp >> 1, j = sp & 1;
        size_t ob = (size_t)(fzb + i) * 4096 + (size_t)(fyb + j) * 64 + 2 * w;
#pragma unroll
        for (int k = 0; k < 4; ++k) {
            float2 v2 = make_float2(acc[2 * sp][k], acc[2 * sp + 1][k]);
            *(float2*)(out + (size_t)(g * 4 + k) * FV + ob) = v2;
        }
    }
}

extern "C" void kernel_launch(void* const* d_in, const int* in_sizes, int n_in,
                              void* d_out, int out_size, void* d_ws, size_t ws_size,
                              hipStream_t stream) {
    const float* x  = (const float*)d_in[0];
    const float* Wc = (const float*)d_in[1];
    const float* bc = (const float*)d_in[2];
    const float* We = (const float*)d_in[3];
    const float* be = (const float*)d_in[4];
    const float* Wp = (const float*)d_in[5];
    float* out = (float*)d_out;

    float* ws = (float*)d_ws;
    float* y2 = ws;                                        // 216*V f32 = 28.3 MB
    float* xp = y2 + (size_t)216 * V;                      // 32*V  f32 =  4 MB
    unsigned short* Ab2 = (unsigned short*)(xp + (size_t)32 * V);  // 55296*8 bf16 = 0.85 MB
    unsigned short* y1p = Ab2 + (size_t)55296 * 8;         // 34^3*64 bf16 = 5 MB

    kP<<<NBA + NBX + NBW, 256, 0, stream>>>(x, Wc, bc, Wp, We, y1p, xp, Ab2);
    kG<<<dim3(256, 2), 512, 0, stream>>>(Ab2, y1p, be, y2);
    kC<<<1024, 256, 0, stream>>>(y2, xp, out);
}